// Round 8
// baseline (325.293 us; speedup 1.0000x reference)
//
#include <hip/hip_runtime.h>
#include <hip/hip_bf16.h>

// DifferentiableXGB: logits = epilogue(x @ W1^T + b1)
//   split[b,n] = sum_d x[b,d]*W1[n,d] + b1[n]          (n = t*4+k, N=400)
//   S[b,t] = sum_k split[b,t,k]
//   logits[b,j] = sum_t fw[t]*S[b,t]*sum_k sigmoid(split[b,t,k])*fc_w[j,k] + fc_b[j]
//
// V8: small-LDS / multi-block-per-CU regime.
// R7 post-mortem: all 1-block/CU structures plateau ~100-160 us GEMM with
// every pipe <20% busy — the whole-block barrier exposes every drain when
// no second block is resident. The 100 KB B double-buffer was the LDS hog.
// V8: W1 (800 KB bf16) is L2-resident -> B-fragments load DIRECTLY
// global->register (R3 proved this path scratch-clean); LDS holds only the
// A tile (64x64 bf16 dbuf = 16 KB, dma-staged with R7's conflict-free
// swizzle). 512 blocks x 5 waves, >=2 blocks/CU: barrier drains overlap
// the other block's compute (m97/m114 regime).

typedef __bf16 bf16x8 __attribute__((ext_vector_type(8)));
typedef float f32x4 __attribute__((ext_vector_type(4)));

#define B_ROWS 32768
#define D_DIM  1024
#define N_COLS 400
#define BM     64
#define BK     64
#define NCHUNK 16          // 1024 / 64
#define THREADS 320        // 5 waves; wave w owns n-tiles [w*5, w*5+5)
#define NTPW 5
#define MT   4             // 4 m-tiles of 16 -> 64 rows/block

__device__ __forceinline__ unsigned short f2bf(float f) {
    unsigned int u = __float_as_uint(f);
    u += 0x7FFFu + ((u >> 16) & 1u);   // RTNE
    return (unsigned short)(u >> 16);
}
__device__ __forceinline__ unsigned int pk2(float a, float b) {
    return (unsigned int)f2bf(a) | ((unsigned int)f2bf(b) << 16);
}
__device__ __forceinline__ uint4 cvt8u(float4 a, float4 b) {
    uint4 u;
    u.x = pk2(a.x, a.y); u.y = pk2(a.z, a.w);
    u.z = pk2(b.x, b.y); u.w = pk2(b.z, b.w);
    return u;
}
__device__ __forceinline__ bf16x8 cvt8(float4 a, float4 b) {
    return __builtin_bit_cast(bf16x8, cvt8u(a, b));
}

// fp32 -> bf16, 8 elems/thread
__global__ void cvt_f32_bf16_kernel(const float* __restrict__ in,
                                    unsigned short* __restrict__ out) {
    size_t i = ((size_t)blockIdx.x * 256 + threadIdx.x) * 8;
    float4 v0 = *reinterpret_cast<const float4*>(in + i);
    float4 v1 = *reinterpret_cast<const float4*>(in + i + 4);
    *reinterpret_cast<uint4*>(out + i) = cvt8u(v0, v1);
}

// async 16B/lane global->LDS; lds dest = wave-uniform base + lane*16 (HW)
__device__ __forceinline__ void gl_lds16(const unsigned short* g,
                                         unsigned short* l) {
    __builtin_amdgcn_global_load_lds(
        (const __attribute__((address_space(1))) unsigned int*)g,
        (__attribute__((address_space(3))) unsigned int*)l,
        16, 0, 0);
}

// MODE 0: A bf16 (ws) via LDS dma, B bf16 (ws) direct-to-register.
// MODE 2: both fp32, plain loop (correctness insurance, no ws).
template <int MODE>
__global__ __launch_bounds__(THREADS, 3) void xgb_v8(
    const void* __restrict__ a_any,
    const void* __restrict__ b_any,
    const float* __restrict__ b1,
    const float* __restrict__ fw,
    const float* __restrict__ fcw,      // [2,4]
    const float* __restrict__ fcb,      // [2]
    float* __restrict__ out)            // [B,2]
{
    // A tile double-buffer: 64 rows x 64 shorts, swizzled
    // phys_sub = (sub + row) & 7 (16B sub-chunks) -> conflict-free b128.
    __shared__ __align__(16) unsigned short Abuf[2][BM * BK];   // 16 KB
    __shared__ float Pbuf[BM * NTPW * 2];                       // 2.5 KB

    const int tid  = threadIdx.x;
    const int wave = tid >> 6;
    const int lane = tid & 63;
    const int quad = lane >> 4;
    const int l15  = lane & 15;
    const int row0 = blockIdx.x * BM;

    f32x4 acc[MT][NTPW] = {};

    if (MODE == 0) {
        const unsigned short* xb  = (const unsigned short*)a_any;
        const unsigned short* w1b = (const unsigned short*)b_any;

        // ---- A staging: 8 dma instrs (8 rows x 64 shorts each); waves 0..3
        // take 2 each (wave-uniform, static). lane i -> row s*8+(i>>3),
        // fetches logical sub ((i&7)-row)&7 so swizzled layout lands at the
        // HW-linear dest  base + lane*16B.
        const unsigned short* asrc0 = nullptr;
        const unsigned short* asrc1 = nullptr;
        int adst0 = 0, adst1 = 0;
        if (wave < 4) {
            const int s0 = wave * 2, s1 = wave * 2 + 1;
            const int rr = lane >> 3;
            const int r0 = s0 * 8 + rr, r1 = s1 * 8 + rr;
            const int c0 = ((lane & 7) - r0) & 7;
            const int c1 = ((lane & 7) - r1) & 7;
            asrc0 = xb + (size_t)(row0 + r0) * D_DIM + c0 * 8;
            asrc1 = xb + (size_t)(row0 + r1) * D_DIM + c1 * 8;
            adst0 = s0 * 512;
            adst1 = s1 * 512;
        }
        auto stageA = [&](int kc, unsigned short* Ab) {
            if (wave < 4) {
                gl_lds16(asrc0 + kc, Ab + adst0);
                gl_lds16(asrc1 + kc, Ab + adst1);
            }
        };

        // ---- B pointers: n-tile nt = wave*5+n, lane holds W1 row nt*16+l15,
        // k-chunk cols kc + h*32 + quad*8 .. +8 (16B contiguous).
        const unsigned short* bptr[NTPW];
        #pragma unroll
        for (int n = 0; n < NTPW; ++n)
            bptr[n] = w1b + (size_t)((wave * NTPW + n) * 16 + l15) * D_DIM
                          + quad * 8;

        // ---- A frag offsets (shorts): row = m*16+l15, sub = quad+h*4,
        // phys = (sub+row)&7.
        int aoff[2][MT];
        #pragma unroll
        for (int h = 0; h < 2; ++h)
            #pragma unroll
            for (int m = 0; m < MT; ++m) {
                const int row = m * 16 + l15;
                aoff[h][m] = row * 64 + (((quad + h * 4 + row) & 7)) * 8;
            }

        stageA(0, Abuf[0]);
        #pragma unroll 1
        for (int c = 0; c < NCHUNK; ++c) {
            const int cur = c & 1;
            const int kc  = c * BK;
            __syncthreads();     // drains dma(c); protects buf 1-cur reuse
            if (c + 1 < NCHUNK) stageA(kc + BK, Abuf[1 - cur]);

            // B loads for this chunk: 10 x uint4, L2-hot W1
            uint4 Bv[2][NTPW];
            #pragma unroll
            for (int h = 0; h < 2; ++h)
                #pragma unroll
                for (int n = 0; n < NTPW; ++n)
                    Bv[h][n] = *reinterpret_cast<const uint4*>(
                        bptr[n] + kc + h * 32);

            #pragma unroll
            for (int h = 0; h < 2; ++h) {
                bf16x8 afr[MT];
                #pragma unroll
                for (int m = 0; m < MT; ++m)
                    afr[m] = *reinterpret_cast<const bf16x8*>(
                        &Abuf[cur][aoff[h][m]]);
                #pragma unroll
                for (int n = 0; n < NTPW; ++n) {
                    const bf16x8 bfr = __builtin_bit_cast(bf16x8, Bv[h][n]);
                    #pragma unroll
                    for (int m = 0; m < MT; ++m)
                        acc[m][n] = __builtin_amdgcn_mfma_f32_16x16x32_bf16(
                            afr[m], bfr, acc[m][n], 0, 0, 0);
                }
            }
        }
    } else {
        // fallback: both fp32, plain loop
        const float* af = (const float*)a_any
                        + (size_t)(row0 + l15) * D_DIM + quad * 8;
        const float* bf32 = (const float*)b_any
                          + (size_t)(wave * (NTPW * 16) + l15) * D_DIM + quad * 8;
        for (int step = 0; step < 32; ++step) {
            const int off = step * 32;
            bf16x8 afr[MT];
            #pragma unroll
            for (int m = 0; m < MT; ++m) {
                float4 a0 = *reinterpret_cast<const float4*>(af + (size_t)m * 16 * D_DIM + off);
                float4 a1 = *reinterpret_cast<const float4*>(af + (size_t)m * 16 * D_DIM + off + 4);
                afr[m] = cvt8(a0, a1);
            }
            #pragma unroll
            for (int n = 0; n < NTPW; ++n) {
                float4 b0v = *reinterpret_cast<const float4*>(bf32 + (size_t)n * 16 * D_DIM + off);
                float4 b1v = *reinterpret_cast<const float4*>(bf32 + (size_t)n * 16 * D_DIM + off + 4);
                const bf16x8 bfr = cvt8(b0v, b1v);
                #pragma unroll
                for (int m = 0; m < MT; ++m)
                    acc[m][n] = __builtin_amdgcn_mfma_f32_16x16x32_bf16(
                        afr[m], bfr, acc[m][n], 0, 0, 0);
            }
        }
    }

    // ---- epilogue ----
    // C/D layout: col = l15 (within tile), row = quad*4 + reg   [m89/m91]
    const float fcw0 = fcw[l15 & 3];        // fc_w[0][k], k = col&3
    const float fcw1 = fcw[4 + (l15 & 3)];  // fc_w[1][k]

    float p0[MT][4], p1[MT][4];
    #pragma unroll
    for (int m = 0; m < MT; ++m)
        #pragma unroll
        for (int r = 0; r < 4; ++r) { p0[m][r] = 0.f; p1[m][r] = 0.f; }

    #pragma unroll
    for (int n = 0; n < NTPW; ++n) {
        const int col = (wave * NTPW + n) * 16 + l15;   // global n index
        const float bias = b1[col];
        const float tw   = fw[col >> 2];                // final_weight[t]
        #pragma unroll
        for (int m = 0; m < MT; ++m) {
            #pragma unroll
            for (int r = 0; r < 4; ++r) {
                float split = acc[m][n][r] + bias;
                float s = split;                        // sum over k: lanes ^1,^2
                s += __shfl_xor(s, 1);
                s += __shfl_xor(s, 2);
                float leaf = 1.0f / (1.0f + __expf(-split));
                float val  = tw * leaf * s;
                p0[m][r] += val * fcw0;
                p1[m][r] += val * fcw1;
            }
        }
    }

    #pragma unroll
    for (int m = 0; m < MT; ++m) {
        #pragma unroll
        for (int r = 0; r < 4; ++r) {
            float a0s = p0[m][r], a1s = p1[m][r];
            #pragma unroll
            for (int mask = 1; mask < 16; mask <<= 1) {
                a0s += __shfl_xor(a0s, mask);
                a1s += __shfl_xor(a1s, mask);
            }
            const int row = m * 16 + quad * 4 + r;      // 0..63 within block
            if (l15 == 0) Pbuf[(row * NTPW + wave) * 2 + 0] = a0s;
            if (l15 == 1) Pbuf[(row * NTPW + wave) * 2 + 1] = a1s;
        }
    }
    __syncthreads();

    if (tid < 2 * BM) {
        const int r = tid >> 1, j = tid & 1;
        float s = fcb[j];
        #pragma unroll
        for (int w = 0; w < NTPW; ++w)
            s += Pbuf[(r * NTPW + w) * 2 + j];
        out[(row0 + r) * 2 + j] = s;
    }
}

extern "C" void kernel_launch(void* const* d_in, const int* in_sizes, int n_in,
                              void* d_out, int out_size, void* d_ws, size_t ws_size,
                              hipStream_t stream) {
    const float* x   = (const float*)d_in[0];
    const float* W1  = (const float*)d_in[1];
    const float* b1  = (const float*)d_in[2];
    const float* fw  = (const float*)d_in[3];
    const float* fcw = (const float*)d_in[4];
    const float* fcb = (const float*)d_in[5];
    float* out = (float*)d_out;

    const size_t x_elems  = (size_t)B_ROWS * D_DIM;   // 33,554,432
    const size_t w1_elems = (size_t)N_COLS * D_DIM;   // 409,600
    const size_t need_full = (x_elems + w1_elems) * sizeof(unsigned short);

    if (ws_size >= need_full) {
        unsigned short* xb  = (unsigned short*)d_ws;
        unsigned short* w1b = xb + x_elems;
        cvt_f32_bf16_kernel<<<(int)(x_elems / 2048), 256, 0, stream>>>(x, xb);
        cvt_f32_bf16_kernel<<<(int)(w1_elems / 2048), 256, 0, stream>>>(W1, w1b);
        xgb_v8<0><<<B_ROWS / BM, THREADS, 0, stream>>>(
            (const void*)xb, (const void*)w1b, b1, fw, fcw, fcb, out);
    } else {
        xgb_v8<2><<<B_ROWS / BM, THREADS, 0, stream>>>(
            (const void*)x, (const void*)W1, b1, fw, fcw, fcb, out);
    }
}